// Round 4
// baseline (306.603 us; speedup 1.0000x reference)
//
#include <hip/hip_runtime.h>
#include <hip/hip_bf16.h>

// Problem constants (fixed by the reference: B=4,S=2048,D=1024,E=8,H=1024)
#define T_TOK 8192
#define DDIM  1024
#define NEXP  8
#define HDIM  1024
#define SLOT_CAP 17536   // 137 M-tiles * 128; >= 16384 + 8*127 padding worst case

typedef short bf16x8 __attribute__((ext_vector_type(8)));   // 8 bf16 in 4 VGPRs
typedef float f32x4  __attribute__((ext_vector_type(4)));

// fp32 -> bf16 round-to-nearest-even
static __device__ __forceinline__ unsigned short f2b(float f) {
    union { float f; unsigned int u; } v; v.f = f;
    unsigned int u = v.u;
    u += 0x7fffu + ((u >> 16) & 1u);
    return (unsigned short)(u >> 16);
}

// ---------------------------------------------------------------------------
// K1: routing. One block per token: fp64 logits (selection-exact), softmax
// top-2 renormalized, 2-stage LDS reduction. Fused x -> bf16 conversion.
// ---------------------------------------------------------------------------
__global__ __launch_bounds__(256) void moe_routing(
    const float* __restrict__ x, const float* __restrict__ wg,
    unsigned short* __restrict__ xb,
    int* __restrict__ tok_e, float* __restrict__ tok_g)
{
    __shared__ double red[256 * 9];   // [thread][expert], stride 9 (bank spread)
    __shared__ double part[64];
    __shared__ double lf[NEXP];

    int t   = blockIdx.x;
    int tid = threadIdx.x;

    float4 xv = ((const float4*)(x + (size_t)t * DDIM))[tid];
    ushort4 xs;
    xs.x = f2b(xv.x); xs.y = f2b(xv.y); xs.z = f2b(xv.z); xs.w = f2b(xv.w);
    ((ushort4*)(xb + (size_t)t * DDIM))[tid] = xs;

    double s[NEXP];
    #pragma unroll
    for (int e = 0; e < NEXP; e++) s[e] = 0.0;
    const float* wr = wg + (size_t)tid * 4 * NEXP;   // Wg rows d = 4*tid .. 4*tid+3
    #pragma unroll
    for (int j = 0; j < 4; j++) {
        double xj = (double)((&xv.x)[j]);
        #pragma unroll
        for (int e = 0; e < NEXP; e++)
            s[e] += xj * (double)wr[j * NEXP + e];
    }
    #pragma unroll
    for (int e = 0; e < NEXP; e++) red[tid * 9 + e] = s[e];
    __syncthreads();

    if (tid < 64) {                    // stage B: 8 partials per expert
        int e = tid >> 3, p = tid & 7;
        double acc = 0.0;
        for (int i = 0; i < 32; i++) acc += red[(i * 8 + p) * 9 + e];
        part[tid] = acc;
    }
    __syncthreads();
    if (tid < NEXP) {                  // stage C: final 8 -> 1 per expert
        double acc = 0.0;
        #pragma unroll
        for (int p = 0; p < 8; p++) acc += part[tid * 8 + p];
        lf[tid] = acc;
    }
    __syncthreads();

    if (tid == 0) {
        double l[NEXP];
        #pragma unroll
        for (int e = 0; e < NEXP; e++) l[e] = lf[e];
        // top-2, first-index-on-tie (matches jax.lax.top_k)
        int e0 = 0;
        for (int e = 1; e < NEXP; e++) if (l[e] > l[e0]) e0 = e;
        int e1 = (e0 == 0) ? 1 : 0;
        for (int e = 0; e < NEXP; e++) if (e != e0 && l[e] > l[e1]) e1 = e;
        double g0 = 1.0 / (1.0 + exp(l[e1] - l[e0]));   // renorm top-2 softmax
        double g1 = 1.0 - g0;
        tok_e[2*t] = e0; tok_e[2*t+1] = e1;
        tok_g[2*t] = (float)g0; tok_g[2*t+1] = (float)g1;
    }
}

// K1b: per-expert histogram. LDS hist then 8 global atomics per block.
__global__ __launch_bounds__(256) void moe_count(
    const int* __restrict__ tok_e, int* __restrict__ counts)
{
    __shared__ int h[NEXP];
    if (threadIdx.x < NEXP) h[threadIdx.x] = 0;
    __syncthreads();
    int t = blockIdx.x * 256 + threadIdx.x;
    atomicAdd(&h[tok_e[2*t]], 1);
    atomicAdd(&h[tok_e[2*t+1]], 1);
    __syncthreads();
    if (threadIdx.x < NEXP) atomicAdd(&counts[threadIdx.x], h[threadIdx.x]);
}

// K2: 128-aligned exclusive prefix over 8 expert counts; init cursors.
__global__ void moe_offsets(const int* __restrict__ counts, int* __restrict__ meta,
                            int* __restrict__ cursor) {
    if (threadIdx.x == 0 && blockIdx.x == 0) {
        int off = 0;
        for (int e = 0; e < NEXP; e++) {
            meta[e] = off;
            cursor[e] = off;
            off += (counts[e] + 127) & ~127;
        }
        meta[NEXP] = off;   // padded total
    }
}

// K3: slot assignment. LDS-atomic local ranks + one cursor bump/expert/block.
__global__ __launch_bounds__(256) void moe_slotfill(
    const int* __restrict__ tok_e, const float* __restrict__ tok_g,
    int* __restrict__ cursor,
    int* __restrict__ slot_token, float* __restrict__ slot_gate)
{
    __shared__ int h[NEXP];
    __shared__ int base[NEXP];
    if (threadIdx.x < NEXP) h[threadIdx.x] = 0;
    __syncthreads();
    int t = blockIdx.x * 256 + threadIdx.x;
    int e0 = tok_e[2*t],     e1 = tok_e[2*t + 1];
    int r0 = atomicAdd(&h[e0], 1);
    int r1 = atomicAdd(&h[e1], 1);
    __syncthreads();
    if (threadIdx.x < NEXP)
        base[threadIdx.x] = atomicAdd(&cursor[threadIdx.x], h[threadIdx.x]);
    __syncthreads();
    int s0 = base[e0] + r0, s1 = base[e1] + r1;
    slot_token[s0] = t; slot_gate[s0] = tok_g[2*t];
    slot_token[s1] = t; slot_gate[s1] = tok_g[2*t + 1];
}

// K4: We [E][D][H] fp32 -> Wt [E][H][D] bf16 (transpose for GEMM B loads).
__global__ __launch_bounds__(256) void moe_wtrans(
    const float* __restrict__ we, unsigned short* __restrict__ wt)
{
    __shared__ unsigned short tile[64][65];
    int e  = blockIdx.z;
    int d0 = blockIdx.y * 64;
    int h0 = blockIdx.x * 64;
    int c  = threadIdx.x & 63;
    int r4 = threadIdx.x >> 6;
    #pragma unroll
    for (int i = 0; i < 64; i += 4)
        tile[r4 + i][c] = f2b(we[((size_t)e * DDIM + d0 + r4 + i) * HDIM + h0 + c]);
    __syncthreads();
    #pragma unroll
    for (int i = 0; i < 64; i += 4)
        wt[((size_t)e * HDIM + h0 + r4 + i) * DDIM + d0 + c] = tile[c][r4 + i];
}

// ---------------------------------------------------------------------------
// K5: grouped gather-GEMM, software-pipelined with RAW BARRIERS.
// R3 lesson: __syncthreads() emits s_waitcnt vmcnt(0) before s_barrier, which
// drains the prefetched global loads every iteration -> MfmaUtil stuck at 11%.
// Fix: s_waitcnt lgkmcnt(0)-only (imm 0xC07F) + raw s_barrier, so prefetch
// loads stay in flight across the barrier (AITER-style fine-grained waits).
// Distance-2 register prefetch (2 reg sets, unroll-2) covers ~2 compute
// phases of load latency. Double-buffered LDS; hazards:
//  RAW: own ds_writes drained by lgkm(0) before barrier, then all read.
//  WAR: a wave drains ALL its LDS ops (incl. prior-iter ds_reads) at the
//       lgkm(0) before barrier k; writes to that buffer occur only after
//       barrier k+1 -> no overwrite of in-flight reads.
// asm memory clobbers stop LLVM moving LDS ops across s_barrier (IntrNoMem).
// LDS k-chunk XOR swizzle keeps frag ds_read_b128 at 2-way (free, m136).
// ---------------------------------------------------------------------------
__global__ __launch_bounds__(256, 4) void moe_gemm(
    const unsigned short* __restrict__ xb,   // [T][D] bf16
    const unsigned short* __restrict__ wt,   // [E][H][D] bf16
    const float* __restrict__ be,            // [E][H]
    const int* __restrict__ slot_token,
    const float* __restrict__ slot_gate,
    const int* __restrict__ meta,
    float* __restrict__ out)                 // [T][H] fp32, pre-zeroed
{
    __shared__ __align__(16) unsigned short As[2][128 * 32];
    __shared__ __align__(16) unsigned short Bs[2][128 * 32];

    int m0 = blockIdx.y * 128;
    if (m0 >= meta[NEXP]) return;
    int n0 = blockIdx.x * 128;

    int e = 0;
    #pragma unroll
    for (int i = 1; i < NEXP; i++) if (m0 >= meta[i]) e = i;

    int tid  = threadIdx.x;
    int lane = tid & 63, wv = tid >> 6;

    // Staging: thread t handles rows r0=t>>2 and r0+64, 16B k-chunk c=t&3.
    int r0  = tid >> 2, c = tid & 3;
    int kus = c * 8;                          // ushort offset inside 32-k slab
    int tA0 = slot_token[m0 + r0];       if (tA0 < 0) tA0 = 0;
    int tA1 = slot_token[m0 + r0 + 64];  if (tA1 < 0) tA1 = 0;
    const unsigned short* gA0 = xb + (size_t)tA0 * DDIM + kus;
    const unsigned short* gA1 = xb + (size_t)tA1 * DDIM + kus;
    const unsigned short* gB0 = wt + ((size_t)e * HDIM + n0 + r0) * DDIM + kus;
    const unsigned short* gB1 = gB0 + (size_t)64 * DDIM;
    // swizzled LDS write offset; f(r0+64)==f(r0) so row+64 is just +2048
    int w0 = r0 * 32 + ((c ^ ((r0 >> 1) & 3)) * 8);

    f32x4 acc[4][4];
    #pragma unroll
    for (int i = 0; i < 4; i++)
        #pragma unroll
        for (int j = 0; j < 4; j++) acc[i][j] = (f32x4){0.f, 0.f, 0.f, 0.f};

    int wm = (wv >> 1) * 64, wn = (wv & 1) * 64;
    int l16 = lane & 15, quad = lane >> 4;
    int f = (l16 >> 1) & 3;                   // == (row>>1)&3 for all frag rows
    int rdA[4], rdB[4];
    #pragma unroll
    for (int i = 0; i < 4; i++) {
        rdA[i] = (wm + i * 16 + l16) * 32 + ((quad ^ f) * 8);
        rdB[i] = (wn + i * 16 + l16) * 32 + ((quad ^ f) * 8);
    }

    // Distance-2 prefetch: reg set s holds tile (k) with k%2==s.
    bf16x8 pa0[2], pa1[2], pb0[2], pb1[2];
    #pragma unroll
    for (int s = 0; s < 2; s++) {
        int ko = s * 32;
        pa0[s] = *(const bf16x8*)(gA0 + ko);
        pa1[s] = *(const bf16x8*)(gA1 + ko);
        pb0[s] = *(const bf16x8*)(gB0 + ko);
        pb1[s] = *(const bf16x8*)(gB1 + ko);
    }

#define KSTEP(kc, s)                                                          \
    {                                                                         \
        unsigned short* A = As[s];                                            \
        unsigned short* B = Bs[s];                                            \
        *(bf16x8*)(A + w0)        = pa0[s];   /* auto vmcnt wait on loads */  \
        *(bf16x8*)(A + w0 + 2048) = pa1[s];                                   \
        *(bf16x8*)(B + w0)        = pb0[s];                                   \
        *(bf16x8*)(B + w0 + 2048) = pb1[s];                                   \
        int ko = (((kc) + 2) & 31) * 32;      /* wrap keeps loads in-bounds */\
        pa0[s] = *(const bf16x8*)(gA0 + ko);                                  \
        pa1[s] = *(const bf16x8*)(gA1 + ko);                                  \
        pb0[s] = *(const bf16x8*)(gB0 + ko);                                  \
        pb1[s] = *(const bf16x8*)(gB1 + ko);                                  \
        asm volatile("" ::: "memory");                                        \
        __builtin_amdgcn_s_waitcnt(0xC07F);   /* lgkmcnt(0) ONLY, vm free */  \
        __builtin_amdgcn_s_barrier();                                         \
        asm volatile("" ::: "memory");                                        \
        bf16x8 af[4], bfr[4];                                                 \
        _Pragma("unroll")                                                     \
        for (int i = 0; i < 4; i++) {                                         \
            af[i]  = *(const bf16x8*)(A + rdA[i]);                            \
            bfr[i] = *(const bf16x8*)(B + rdB[i]);                            \
        }                                                                     \
        _Pragma("unroll")                                                     \
        for (int i = 0; i < 4; i++)                                           \
            _Pragma("unroll")                                                 \
            for (int j = 0; j < 4; j++)                                       \
                acc[i][j] = __builtin_amdgcn_mfma_f32_16x16x32_bf16(          \
                    af[i], bfr[j], acc[i][j], 0, 0, 0);                       \
    }

    #pragma unroll 1
    for (int kk = 0; kk < 32; kk += 2) {
        KSTEP(kk, 0)
        KSTEP(kk + 1, 1)
    }
#undef KSTEP

    // Epilogue: C/D layout col=lane&15, row=quad*4+reg (m89/m91)
    #pragma unroll
    for (int i = 0; i < 4; i++) {
        #pragma unroll
        for (int r = 0; r < 4; r++) {
            int row  = wm + i * 16 + quad * 4 + r;
            int slot = m0 + row;
            int t = slot_token[slot];
            if (t < 0) continue;              // padding slot
            float g = slot_gate[slot];
            float* op = out + (size_t)t * HDIM + n0;
            #pragma unroll
            for (int j = 0; j < 4; j++) {
                int col = wn + j * 16 + l16;
                atomicAdd(op + col, g * (acc[i][j][r] + be[e * HDIM + n0 + col]));
            }
        }
    }
}

extern "C" void kernel_launch(void* const* d_in, const int* in_sizes, int n_in,
                              void* d_out, int out_size, void* d_ws, size_t ws_size,
                              hipStream_t stream) {
    const float* x  = (const float*)d_in[0];   // [B,S,D] fp32
    const float* wg = (const float*)d_in[1];   // [D,E]
    const float* we = (const float*)d_in[2];   // [E,D,H]
    const float* be = (const float*)d_in[3];   // [E,H]
    float* out = (float*)d_out;

    char* ws = (char*)d_ws;
    size_t o = 0;
    auto alloc = [&](size_t bytes) -> void* {
        void* p = ws + o;
        o = (o + bytes + 255) & ~(size_t)255;
        return p;
    };
    unsigned short* xb   = (unsigned short*)alloc((size_t)T_TOK * DDIM * 2);
    unsigned short* wtb  = (unsigned short*)alloc((size_t)NEXP * HDIM * DDIM * 2);
    int*   slot_token    = (int*)  alloc((size_t)SLOT_CAP * 4);
    float* slot_gate     = (float*)alloc((size_t)SLOT_CAP * 4);
    int*   counts        = (int*)  alloc(NEXP * 4);
    int*   meta          = (int*)  alloc((NEXP + 1) * 4);
    int*   cursor        = (int*)  alloc(NEXP * 4);
    int*   tok_e         = (int*)  alloc((size_t)T_TOK * 2 * 4);
    float* tok_g         = (float*)alloc((size_t)T_TOK * 2 * 4);

    hipMemsetAsync(counts, 0, NEXP * 4, stream);
    hipMemsetAsync(slot_token, 0xFF, (size_t)SLOT_CAP * 4, stream);   // -1 = pad
    hipMemsetAsync(d_out, 0, (size_t)out_size * 4, stream);

    moe_routing<<<T_TOK, 256, 0, stream>>>(x, wg, xb, tok_e, tok_g);
    moe_count<<<T_TOK / 256, 256, 0, stream>>>(tok_e, counts);
    moe_offsets<<<1, 64, 0, stream>>>(counts, meta, cursor);
    moe_slotfill<<<T_TOK / 256, 256, 0, stream>>>(tok_e, tok_g, cursor,
                                                  slot_token, slot_gate);
    moe_wtrans<<<dim3(HDIM / 64, DDIM / 64, NEXP), 256, 0, stream>>>(we, wtb);
    moe_gemm<<<dim3(HDIM / 128, SLOT_CAP / 128), 256, 0, stream>>>(
        xb, wtb, be, slot_token, slot_gate, meta, out);
}

// Round 5
// 274.907 us; speedup vs baseline: 1.1153x; 1.1153x over previous
//
#include <hip/hip_runtime.h>
#include <hip/hip_bf16.h>

// Problem constants (fixed by the reference: B=4,S=2048,D=1024,E=8,H=1024)
#define T_TOK 8192
#define DDIM  1024
#define NEXP  8
#define HDIM  1024
#define SLOT_CAP 17536   // 137 M-tiles * 128; >= 16384 + 8*127 padding worst case

typedef short bf16x8 __attribute__((ext_vector_type(8)));   // 8 bf16 in 4 VGPRs
typedef float f32x4  __attribute__((ext_vector_type(4)));

typedef const __attribute__((address_space(1))) unsigned int* gas_ptr;
typedef __attribute__((address_space(3))) unsigned int*       las_ptr;
#define GLD16(gp, lp) __builtin_amdgcn_global_load_lds((gas_ptr)(gp), (las_ptr)(lp), 16, 0, 0)

// fp32 -> bf16 round-to-nearest-even
static __device__ __forceinline__ unsigned short f2b(float f) {
    union { float f; unsigned int u; } v; v.f = f;
    unsigned int u = v.u;
    u += 0x7fffu + ((u >> 16) & 1u);
    return (unsigned short)(u >> 16);
}

// ---------------------------------------------------------------------------
// K1: routing. One block per token: fp64 logits (selection-exact), softmax
// top-2 renormalized, 2-stage LDS reduction. Fused x -> bf16 conversion.
// ---------------------------------------------------------------------------
__global__ __launch_bounds__(256) void moe_routing(
    const float* __restrict__ x, const float* __restrict__ wg,
    unsigned short* __restrict__ xb,
    int* __restrict__ tok_e, float* __restrict__ tok_g)
{
    __shared__ double red[256 * 9];   // [thread][expert], stride 9 (bank spread)
    __shared__ double part[64];
    __shared__ double lf[NEXP];

    int t   = blockIdx.x;
    int tid = threadIdx.x;

    float4 xv = ((const float4*)(x + (size_t)t * DDIM))[tid];
    ushort4 xs;
    xs.x = f2b(xv.x); xs.y = f2b(xv.y); xs.z = f2b(xv.z); xs.w = f2b(xv.w);
    ((ushort4*)(xb + (size_t)t * DDIM))[tid] = xs;

    double s[NEXP];
    #pragma unroll
    for (int e = 0; e < NEXP; e++) s[e] = 0.0;
    const float* wr = wg + (size_t)tid * 4 * NEXP;   // Wg rows d = 4*tid .. 4*tid+3
    #pragma unroll
    for (int j = 0; j < 4; j++) {
        double xj = (double)((&xv.x)[j]);
        #pragma unroll
        for (int e = 0; e < NEXP; e++)
            s[e] += xj * (double)wr[j * NEXP + e];
    }
    #pragma unroll
    for (int e = 0; e < NEXP; e++) red[tid * 9 + e] = s[e];
    __syncthreads();

    if (tid < 64) {                    // stage B: 8 partials per expert
        int e = tid >> 3, p = tid & 7;
        double acc = 0.0;
        for (int i = 0; i < 32; i++) acc += red[(i * 8 + p) * 9 + e];
        part[tid] = acc;
    }
    __syncthreads();
    if (tid < NEXP) {                  // stage C: final 8 -> 1 per expert
        double acc = 0.0;
        #pragma unroll
        for (int p = 0; p < 8; p++) acc += part[tid * 8 + p];
        lf[tid] = acc;
    }
    __syncthreads();

    if (tid == 0) {
        double l[NEXP];
        #pragma unroll
        for (int e = 0; e < NEXP; e++) l[e] = lf[e];
        // top-2, first-index-on-tie (matches jax.lax.top_k)
        int e0 = 0;
        for (int e = 1; e < NEXP; e++) if (l[e] > l[e0]) e0 = e;
        int e1 = (e0 == 0) ? 1 : 0;
        for (int e = 0; e < NEXP; e++) if (e != e0 && l[e] > l[e1]) e1 = e;
        double g0 = 1.0 / (1.0 + exp(l[e1] - l[e0]));   // renorm top-2 softmax
        double g1 = 1.0 - g0;
        tok_e[2*t] = e0; tok_e[2*t+1] = e1;
        tok_g[2*t] = (float)g0; tok_g[2*t+1] = (float)g1;
    }
}

// K1b: per-expert histogram. LDS hist then 8 global atomics per block.
__global__ __launch_bounds__(256) void moe_count(
    const int* __restrict__ tok_e, int* __restrict__ counts)
{
    __shared__ int h[NEXP];
    if (threadIdx.x < NEXP) h[threadIdx.x] = 0;
    __syncthreads();
    int t = blockIdx.x * 256 + threadIdx.x;
    atomicAdd(&h[tok_e[2*t]], 1);
    atomicAdd(&h[tok_e[2*t+1]], 1);
    __syncthreads();
    if (threadIdx.x < NEXP) atomicAdd(&counts[threadIdx.x], h[threadIdx.x]);
}

// K2: 128-aligned exclusive prefix over 8 expert counts; init cursors.
__global__ void moe_offsets(const int* __restrict__ counts, int* __restrict__ meta,
                            int* __restrict__ cursor) {
    if (threadIdx.x == 0 && blockIdx.x == 0) {
        int off = 0;
        for (int e = 0; e < NEXP; e++) {
            meta[e] = off;
            cursor[e] = off;
            off += (counts[e] + 127) & ~127;
        }
        meta[NEXP] = off;   // padded total
    }
}

// K3: slot assignment. LDS-atomic local ranks + one cursor bump/expert/block.
__global__ __launch_bounds__(256) void moe_slotfill(
    const int* __restrict__ tok_e, const float* __restrict__ tok_g,
    int* __restrict__ cursor,
    int* __restrict__ slot_token, float* __restrict__ slot_gate)
{
    __shared__ int h[NEXP];
    __shared__ int base[NEXP];
    if (threadIdx.x < NEXP) h[threadIdx.x] = 0;
    __syncthreads();
    int t = blockIdx.x * 256 + threadIdx.x;
    int e0 = tok_e[2*t],     e1 = tok_e[2*t + 1];
    int r0 = atomicAdd(&h[e0], 1);
    int r1 = atomicAdd(&h[e1], 1);
    __syncthreads();
    if (threadIdx.x < NEXP)
        base[threadIdx.x] = atomicAdd(&cursor[threadIdx.x], h[threadIdx.x]);
    __syncthreads();
    int s0 = base[e0] + r0, s1 = base[e1] + r1;
    slot_token[s0] = t; slot_gate[s0] = tok_g[2*t];
    slot_token[s1] = t; slot_gate[s1] = tok_g[2*t + 1];
}

// K4: We [E][D][H] fp32 -> Wt [E][H][D] bf16 (transpose for GEMM B loads).
__global__ __launch_bounds__(256) void moe_wtrans(
    const float* __restrict__ we, unsigned short* __restrict__ wt)
{
    __shared__ unsigned short tile[64][65];
    int e  = blockIdx.z;
    int d0 = blockIdx.y * 64;
    int h0 = blockIdx.x * 64;
    int c  = threadIdx.x & 63;
    int r4 = threadIdx.x >> 6;
    #pragma unroll
    for (int i = 0; i < 64; i += 4)
        tile[r4 + i][c] = f2b(we[((size_t)e * DDIM + d0 + r4 + i) * HDIM + h0 + c]);
    __syncthreads();
    #pragma unroll
    for (int i = 0; i < 64; i += 4)
        wt[((size_t)e * HDIM + h0 + r4 + i) * DDIM + d0 + c] = tile[c][r4 + i];
}

// ---------------------------------------------------------------------------
// K5: grouped gather-GEMM — GLD16 + triple-buffer + raw-barrier pipeline.
// R4 lesson: register prefetch + launch_bounds cap -> scratch spill (WRITE
// 65->135MB). GLD16 staging costs ZERO data VGPRs. R2 lesson: __syncthreads
// drains vmcnt(0); use s_waitcnt vmcnt(4) + raw s_barrier so the next tile's
// loads stay in flight (AITER-style). Per iter:
//   vmcnt(4)            -- group k landed; group k+1 stays in flight
//   s_barrier           -- all waves' buf-k chunks visible
//   issue group k+2     -- AFTER barrier: buf (k+2)%3 was last read at iter
//                          k-1, those ds_reads retired before their wave
//                          reached barrier k -> no WAR race
//   ds_read + 16 MFMA on buf k%3
// XOR k-chunk swizzle done by permuting each staging lane's global source
// column (kc = (lane&3) ^ ((row>>1)&3)) -- LDS image gets the swizzle within
// GLD16's lane-linear constraint; frag ds_read_b128 stays 2-way (free, m136).
// R2's unswizzled GLD16 layout was 8-way (4.3M conflict cycles).
// ---------------------------------------------------------------------------
__global__ __launch_bounds__(256) void moe_gemm(
    const unsigned short* __restrict__ xb,   // [T][D] bf16
    const unsigned short* __restrict__ wt,   // [E][H][D] bf16
    const float* __restrict__ be,            // [E][H]
    const int* __restrict__ slot_token,
    const float* __restrict__ slot_gate,
    const int* __restrict__ meta,
    float* __restrict__ out)                 // [T][H] fp32, pre-zeroed
{
    __shared__ __align__(16) unsigned short As[3][128 * 32];
    __shared__ __align__(16) unsigned short Bs[3][128 * 32];

    int m0 = blockIdx.y * 128;
    if (m0 >= meta[NEXP]) return;
    int n0 = blockIdx.x * 128;

    int e = 0;
    #pragma unroll
    for (int i = 1; i < NEXP; i++) if (m0 >= meta[i]) e = i;

    int tid  = threadIdx.x;
    int lane = tid & 63, wv = tid >> 6;

    // Staging geometry: wave w owns 16-row chunks 2w,2w+1 of A and B.
    // Lane i -> local row i>>2, phys 16B slot i&3; global source column is
    // the swizzle-permuted logical chunk (f(r) identical for r and r+16).
    int rA = 32 * wv + (lane >> 2);           // chunk-pair base row
    int kc = (((lane & 3) ^ ((rA >> 1) & 3)) * 8);   // ushort offset in 64B row
    int tA0 = slot_token[m0 + rA];       if (tA0 < 0) tA0 = 0;
    int tA1 = slot_token[m0 + rA + 16];  if (tA1 < 0) tA1 = 0;
    const unsigned short* gA0 = xb + (size_t)tA0 * DDIM + kc;
    const unsigned short* gA1 = xb + (size_t)tA1 * DDIM + kc;
    const unsigned short* gB0 = wt + ((size_t)e * HDIM + n0 + rA) * DDIM + kc;
    const unsigned short* gB1 = gB0 + (size_t)16 * DDIM;
    int c0 = (2 * wv) * 512;                  // wave-uniform LDS chunk bases
    int c1 = c0 + 512;

    f32x4 acc[4][4];
    #pragma unroll
    for (int i = 0; i < 4; i++)
        #pragma unroll
        for (int j = 0; j < 4; j++) acc[i][j] = (f32x4){0.f, 0.f, 0.f, 0.f};

    int wm = (wv >> 1) * 64, wn = (wv & 1) * 64;
    int l16 = lane & 15, quad = lane >> 4;
    int f = (l16 >> 1) & 3;                   // == (row>>1)&3 for all frag rows
    int rdA[4], rdB[4];
    #pragma unroll
    for (int i = 0; i < 4; i++) {
        rdA[i] = (wm + i * 16 + l16) * 32 + ((quad ^ f) * 8);
        rdB[i] = (wn + i * 16 + l16) * 32 + ((quad ^ f) * 8);
    }

#define ISSUE(kkv, Ab, Bb)                                                    \
    {                                                                         \
        int ko = (kkv) * 32;                                                  \
        GLD16(gA0 + ko, (Ab) + c0);                                           \
        GLD16(gA1 + ko, (Ab) + c1);                                           \
        GLD16(gB0 + ko, (Bb) + c0);                                           \
        GLD16(gB1 + ko, (Bb) + c1);                                           \
    }

#define COMPUTE(Ab, Bb)                                                       \
    {                                                                         \
        bf16x8 af[4], bfr[4];                                                 \
        _Pragma("unroll")                                                     \
        for (int i = 0; i < 4; i++) {                                         \
            af[i]  = *(const bf16x8*)((Ab) + rdA[i]);                         \
            bfr[i] = *(const bf16x8*)((Bb) + rdB[i]);                         \
        }                                                                     \
        _Pragma("unroll")                                                     \
        for (int i = 0; i < 4; i++)                                           \
            _Pragma("unroll")                                                 \
            for (int j = 0; j < 4; j++)                                       \
                acc[i][j] = __builtin_amdgcn_mfma_f32_16x16x32_bf16(          \
                    af[i], bfr[j], acc[i][j], 0, 0, 0);                       \
    }

    unsigned short *A0 = As[0], *A1 = As[1], *A2 = As[2];
    unsigned short *B0 = Bs[0], *B1 = Bs[1], *B2 = Bs[2];

    ISSUE(0, A0, B0)
    ISSUE(1, A1, B1)

    #pragma unroll 1
    for (int kk = 0; kk < 31; ++kk) {
        asm volatile("" ::: "memory");
        __builtin_amdgcn_s_waitcnt(0x0F74);   // vmcnt(4): group kk landed
        __builtin_amdgcn_s_barrier();
        asm volatile("" ::: "memory");
        if (kk < 30) ISSUE(kk + 2, A2, B2)    // after barrier: WAR-safe
        COMPUTE(A0, B0)
        unsigned short* tA = A0; A0 = A1; A1 = A2; A2 = tA;   // rotate bufs
        unsigned short* tB = B0; B0 = B1; B1 = B2; B2 = tB;
    }
    asm volatile("" ::: "memory");
    __builtin_amdgcn_s_waitcnt(0x0F70);       // vmcnt(0): last group landed
    __builtin_amdgcn_s_barrier();
    asm volatile("" ::: "memory");
    COMPUTE(A0, B0)
#undef ISSUE
#undef COMPUTE

    // Epilogue: C/D layout col=lane&15, row=quad*4+reg (m89/m91)
    #pragma unroll
    for (int i = 0; i < 4; i++) {
        #pragma unroll
        for (int r = 0; r < 4; r++) {
            int row  = wm + i * 16 + quad * 4 + r;
            int slot = m0 + row;
            int t = slot_token[slot];
            if (t < 0) continue;              // padding slot
            float g = slot_gate[slot];
            float* op = out + (size_t)t * HDIM + n0;
            #pragma unroll
            for (int j = 0; j < 4; j++) {
                int col = wn + j * 16 + l16;
                atomicAdd(op + col, g * (acc[i][j][r] + be[e * HDIM + n0 + col]));
            }
        }
    }
}

extern "C" void kernel_launch(void* const* d_in, const int* in_sizes, int n_in,
                              void* d_out, int out_size, void* d_ws, size_t ws_size,
                              hipStream_t stream) {
    const float* x  = (const float*)d_in[0];   // [B,S,D] fp32
    const float* wg = (const float*)d_in[1];   // [D,E]
    const float* we = (const float*)d_in[2];   // [E,D,H]
    const float* be = (const float*)d_in[3];   // [E,H]
    float* out = (float*)d_out;

    char* ws = (char*)d_ws;
    size_t o = 0;
    auto alloc = [&](size_t bytes) -> void* {
        void* p = ws + o;
        o = (o + bytes + 255) & ~(size_t)255;
        return p;
    };
    unsigned short* xb   = (unsigned short*)alloc((size_t)T_TOK * DDIM * 2);
    unsigned short* wtb  = (unsigned short*)alloc((size_t)NEXP * HDIM * DDIM * 2);
    int*   slot_token    = (int*)  alloc((size_t)SLOT_CAP * 4);
    float* slot_gate     = (float*)alloc((size_t)SLOT_CAP * 4);
    int*   counts        = (int*)  alloc(NEXP * 4);
    int*   meta          = (int*)  alloc((NEXP + 1) * 4);
    int*   cursor        = (int*)  alloc(NEXP * 4);
    int*   tok_e         = (int*)  alloc((size_t)T_TOK * 2 * 4);
    float* tok_g         = (float*)alloc((size_t)T_TOK * 2 * 4);

    hipMemsetAsync(counts, 0, NEXP * 4, stream);
    hipMemsetAsync(slot_token, 0xFF, (size_t)SLOT_CAP * 4, stream);   // -1 = pad
    hipMemsetAsync(d_out, 0, (size_t)out_size * 4, stream);

    moe_routing<<<T_TOK, 256, 0, stream>>>(x, wg, xb, tok_e, tok_g);
    moe_count<<<T_TOK / 256, 256, 0, stream>>>(tok_e, counts);
    moe_offsets<<<1, 64, 0, stream>>>(counts, meta, cursor);
    moe_slotfill<<<T_TOK / 256, 256, 0, stream>>>(tok_e, tok_g, cursor,
                                                  slot_token, slot_gate);
    moe_wtrans<<<dim3(HDIM / 64, DDIM / 64, NEXP), 256, 0, stream>>>(we, wtb);
    moe_gemm<<<dim3(HDIM / 128, SLOT_CAP / 128), 256, 0, stream>>>(
        xb, wtb, be, slot_token, slot_gate, meta, out);
}

// Round 6
// 251.134 us; speedup vs baseline: 1.2209x; 1.0947x over previous
//
#include <hip/hip_runtime.h>
#include <hip/hip_bf16.h>

// Problem constants (fixed by the reference: B=4,S=2048,D=1024,E=8,H=1024)
#define T_TOK 8192
#define DDIM  1024
#define NEXP  8
#define HDIM  1024
#define SLOT_CAP 17536   // 137 M-tiles * 128; >= 16384 + 8*127 padding worst case

typedef short bf16x8 __attribute__((ext_vector_type(8)));   // 8 bf16 in 4 VGPRs
typedef float f32x4  __attribute__((ext_vector_type(4)));

typedef const __attribute__((address_space(1))) unsigned int* gas_ptr;
typedef __attribute__((address_space(3))) unsigned int*       las_ptr;
#define GLD16(gp, lp) __builtin_amdgcn_global_load_lds((gas_ptr)(gp), (las_ptr)(lp), 16, 0, 0)

// fp32 -> bf16 round-to-nearest-even
static __device__ __forceinline__ unsigned short f2b(float f) {
    union { float f; unsigned int u; } v; v.f = f;
    unsigned int u = v.u;
    u += 0x7fffu + ((u >> 16) & 1u);
    return (unsigned short)(u >> 16);
}
static __device__ __forceinline__ float b2f(unsigned short h) {
    union { unsigned int u; float f; } v; v.u = ((unsigned int)h) << 16;
    return v.f;
}

// ---------------------------------------------------------------------------
// K1: routing. One block per token: fp64 logits (selection-exact vs numpy),
// softmax top-2 renormalized, 2-stage LDS reduction. Fused x -> bf16.
// ---------------------------------------------------------------------------
__global__ __launch_bounds__(256) void moe_routing(
    const float* __restrict__ x, const float* __restrict__ wg,
    unsigned short* __restrict__ xb,
    int* __restrict__ tok_e, float* __restrict__ tok_g)
{
    __shared__ double red[256 * 9];   // [thread][expert], stride 9 (bank spread)
    __shared__ double part[64];
    __shared__ double lf[NEXP];

    int t   = blockIdx.x;
    int tid = threadIdx.x;

    float4 xv = ((const float4*)(x + (size_t)t * DDIM))[tid];
    ushort4 xs;
    xs.x = f2b(xv.x); xs.y = f2b(xv.y); xs.z = f2b(xv.z); xs.w = f2b(xv.w);
    ((ushort4*)(xb + (size_t)t * DDIM))[tid] = xs;

    double s[NEXP];
    #pragma unroll
    for (int e = 0; e < NEXP; e++) s[e] = 0.0;
    const float* wr = wg + (size_t)tid * 4 * NEXP;   // Wg rows d = 4*tid .. 4*tid+3
    #pragma unroll
    for (int j = 0; j < 4; j++) {
        double xj = (double)((&xv.x)[j]);
        #pragma unroll
        for (int e = 0; e < NEXP; e++)
            s[e] += xj * (double)wr[j * NEXP + e];
    }
    #pragma unroll
    for (int e = 0; e < NEXP; e++) red[tid * 9 + e] = s[e];
    __syncthreads();

    if (tid < 64) {                    // stage B: 8 partials per expert
        int e = tid >> 3, p = tid & 7;
        double acc = 0.0;
        for (int i = 0; i < 32; i++) acc += red[(i * 8 + p) * 9 + e];
        part[tid] = acc;
    }
    __syncthreads();
    if (tid < NEXP) {                  // stage C: final 8 -> 1 per expert
        double acc = 0.0;
        #pragma unroll
        for (int p = 0; p < 8; p++) acc += part[tid * 8 + p];
        lf[tid] = acc;
    }
    __syncthreads();

    if (tid == 0) {
        double l[NEXP];
        #pragma unroll
        for (int e = 0; e < NEXP; e++) l[e] = lf[e];
        // top-2, first-index-on-tie (matches jax.lax.top_k)
        int e0 = 0;
        for (int e = 1; e < NEXP; e++) if (l[e] > l[e0]) e0 = e;
        int e1 = (e0 == 0) ? 1 : 0;
        for (int e = 0; e < NEXP; e++) if (e != e0 && l[e] > l[e1]) e1 = e;
        double g0 = 1.0 / (1.0 + exp(l[e1] - l[e0]));   // renorm top-2 softmax
        double g1 = 1.0 - g0;
        tok_e[2*t] = e0; tok_e[2*t+1] = e1;
        tok_g[2*t] = (float)g0; tok_g[2*t+1] = (float)g1;
    }
}

// ---------------------------------------------------------------------------
// K2: route-pack — count + prefix + slot assignment fused into ONE single-
// block kernel (was 3 dispatches + 2 memsets; ~10us/dispatch graph overhead).
// 1024 threads x 16 entries. Per-thread register histogram (unrolled
// compare-add, no indexed arrays -> no scratch), Hillis-Steele block scan
// per expert in LDS, thread 0 does 128-aligned meta, then each thread
// assigns its entries' slots deterministically. Also emits tok_slot for the
// combine kernel. No global atomics anywhere.
// ---------------------------------------------------------------------------
__global__ __launch_bounds__(1024) void moe_route_pack(
    const int* __restrict__ tok_e, const float* __restrict__ tok_g,
    int* __restrict__ meta, int* __restrict__ counts,
    int* __restrict__ slot_token, float* __restrict__ slot_gate,
    int* __restrict__ tok_slot)
{
    __shared__ int sc[NEXP][1024];
    __shared__ int meta_s[NEXP + 1];
    int tid = threadIdx.x;

    int ev[16];
    int c[NEXP];
    #pragma unroll
    for (int e = 0; e < NEXP; e++) c[e] = 0;
    #pragma unroll
    for (int i = 0; i < 16; i++) {
        ev[i] = tok_e[tid * 16 + i];
        #pragma unroll
        for (int e = 0; e < NEXP; e++) c[e] += (ev[i] == e);
    }
    #pragma unroll
    for (int e = 0; e < NEXP; e++) sc[e][tid] = c[e];
    __syncthreads();

    for (int off = 1; off < 1024; off <<= 1) {   // inclusive scan per expert
        int add[NEXP];
        #pragma unroll
        for (int e = 0; e < NEXP; e++)
            add[e] = (tid >= off) ? sc[e][tid - off] : 0;
        __syncthreads();
        #pragma unroll
        for (int e = 0; e < NEXP; e++) sc[e][tid] += add[e];
        __syncthreads();
    }

    if (tid == 0) {
        int off = 0;
        for (int e = 0; e < NEXP; e++) {
            int cnt = sc[e][1023];
            meta_s[e] = off; meta[e] = off; counts[e] = cnt;
            off += (cnt + 127) & ~127;
        }
        meta_s[NEXP] = off; meta[NEXP] = off;
    }
    __syncthreads();

    int base[NEXP];
    #pragma unroll
    for (int e = 0; e < NEXP; e++)
        base[e] = meta_s[e] + sc[e][tid] - c[e];   // exclusive base this thread

    #pragma unroll
    for (int i = 0; i < 16; i++) {
        int idx = tid * 16 + i;            // = 2*token + j
        int s = 0;
        #pragma unroll
        for (int e = 0; e < NEXP; e++) s = (ev[i] == e) ? base[e] : s;
        slot_token[s] = idx >> 1;
        slot_gate[s]  = tok_g[idx];
        tok_slot[idx] = s;
        #pragma unroll
        for (int e = 0; e < NEXP; e++) base[e] += (ev[i] == e);
    }
}

// K3: We [E][D][H] fp32 -> Wt [E][H][D] bf16 (transpose for GEMM B loads).
__global__ __launch_bounds__(256) void moe_wtrans(
    const float* __restrict__ we, unsigned short* __restrict__ wt)
{
    __shared__ unsigned short tile[64][65];
    int e  = blockIdx.z;
    int d0 = blockIdx.y * 64;
    int h0 = blockIdx.x * 64;
    int c  = threadIdx.x & 63;
    int r4 = threadIdx.x >> 6;
    #pragma unroll
    for (int i = 0; i < 64; i += 4)
        tile[r4 + i][c] = f2b(we[((size_t)e * DDIM + d0 + r4 + i) * HDIM + h0 + c]);
    __syncthreads();
    #pragma unroll
    for (int i = 0; i < 64; i += 4)
        wt[((size_t)e * HDIM + h0 + r4 + i) * DDIM + d0 + c] = tile[c][r4 + i];
}

// ---------------------------------------------------------------------------
// K4: grouped gather-GEMM. R5 lesson: three different K-loop structures all
// land at 122-128us / MfmaUtil 11% -> the K-loop isn't the only cost. This
// round DECOMPOSES: epilogue no longer does 16.8M fp32 atomicAdds to out;
// it stores y_slot (bf16, plain coalesced stores) and moe_combine does the
// gated 2-way sum. Pad slots detected by rank >= counts[e] (no -1 memset).
// K-loop: GLD16 triple-buffer, vmcnt(4) + raw s_barrier; ISSUE moved AFTER
// COMPUTE so that even if the compiler inserts its own vmcnt(0) before the
// ds_reads (m131 behavior), the drained loads were issued a full iteration
// earlier (distance-1 coverage) instead of just-issued (distance-0).
// ---------------------------------------------------------------------------
__global__ __launch_bounds__(256) void moe_gemm(
    const unsigned short* __restrict__ xb,   // [T][D] bf16
    const unsigned short* __restrict__ wt,   // [E][H][D] bf16
    const float* __restrict__ be,            // [E][H]
    const int* __restrict__ slot_token,
    const int* __restrict__ meta,
    const int* __restrict__ counts,
    unsigned short* __restrict__ y_slot)     // [SLOT_CAP][H] bf16
{
    __shared__ __align__(16) unsigned short As[3][128 * 32];
    __shared__ __align__(16) unsigned short Bs[3][128 * 32];

    int m0 = blockIdx.y * 128;
    if (m0 >= meta[NEXP]) return;
    int n0 = blockIdx.x * 128;

    int e = 0;
    #pragma unroll
    for (int i = 1; i < NEXP; i++) if (m0 >= meta[i]) e = i;
    int lim = meta[e] + counts[e];           // slots >= lim are padding

    int tid  = threadIdx.x;
    int lane = tid & 63, wv = tid >> 6;

    // Staging geometry: wave w owns 16-row chunks 2w,2w+1 of A and B.
    int rA = 32 * wv + (lane >> 2);
    int kc = (((lane & 3) ^ ((rA >> 1) & 3)) * 8);   // swizzled source column
    int sA0 = m0 + rA, sA1 = sA0 + 16;
    int tA0 = (sA0 < lim) ? slot_token[sA0] : 0;     // guard BEFORE deref: pads
    int tA1 = (sA1 < lim) ? slot_token[sA1] : 0;     // hold poison post-R6
    const unsigned short* gA0 = xb + (size_t)tA0 * DDIM + kc;
    const unsigned short* gA1 = xb + (size_t)tA1 * DDIM + kc;
    const unsigned short* gB0 = wt + ((size_t)e * HDIM + n0 + rA) * DDIM + kc;
    const unsigned short* gB1 = gB0 + (size_t)16 * DDIM;
    int c0 = (2 * wv) * 512;
    int c1 = c0 + 512;

    f32x4 acc[4][4];
    #pragma unroll
    for (int i = 0; i < 4; i++)
        #pragma unroll
        for (int j = 0; j < 4; j++) acc[i][j] = (f32x4){0.f, 0.f, 0.f, 0.f};

    int wm = (wv >> 1) * 64, wn = (wv & 1) * 64;
    int l16 = lane & 15, quad = lane >> 4;
    int f = (l16 >> 1) & 3;
    int rdA[4], rdB[4];
    #pragma unroll
    for (int i = 0; i < 4; i++) {
        rdA[i] = (wm + i * 16 + l16) * 32 + ((quad ^ f) * 8);
        rdB[i] = (wn + i * 16 + l16) * 32 + ((quad ^ f) * 8);
    }

#define ISSUE(kkv, Ab, Bb)                                                    \
    {                                                                         \
        int ko = (kkv) * 32;                                                  \
        GLD16(gA0 + ko, (Ab) + c0);                                           \
        GLD16(gA1 + ko, (Ab) + c1);                                           \
        GLD16(gB0 + ko, (Bb) + c0);                                           \
        GLD16(gB1 + ko, (Bb) + c1);                                           \
    }

#define COMPUTE(Ab, Bb)                                                       \
    {                                                                         \
        bf16x8 af[4], bfr[4];                                                 \
        _Pragma("unroll")                                                     \
        for (int i = 0; i < 4; i++) {                                         \
            af[i]  = *(const bf16x8*)((Ab) + rdA[i]);                         \
            bfr[i] = *(const bf16x8*)((Bb) + rdB[i]);                         \
        }                                                                     \
        _Pragma("unroll")                                                     \
        for (int i = 0; i < 4; i++)                                           \
            _Pragma("unroll")                                                 \
            for (int j = 0; j < 4; j++)                                       \
                acc[i][j] = __builtin_amdgcn_mfma_f32_16x16x32_bf16(          \
                    af[i], bfr[j], acc[i][j], 0, 0, 0);                       \
    }

    unsigned short *A0 = As[0], *A1 = As[1], *A2 = As[2];
    unsigned short *B0 = Bs[0], *B1 = Bs[1], *B2 = Bs[2];

    ISSUE(0, A0, B0)
    ISSUE(1, A1, B1)

    #pragma unroll 1
    for (int kk = 0; kk < 32; ++kk) {
        asm volatile("" ::: "memory");
        if (kk == 31) __builtin_amdgcn_s_waitcnt(0x0F70);  // vmcnt(0) tail
        else          __builtin_amdgcn_s_waitcnt(0x0F74);  // vmcnt(4)
        __builtin_amdgcn_s_barrier();
        asm volatile("" ::: "memory");
        COMPUTE(A0, B0)
        if (kk < 30) ISSUE(kk + 2, A2, B2)    // after compute: distance-1 even
                                              // if compiler drains at ds_read
        unsigned short* tA = A0; A0 = A1; A1 = A2; A2 = tA;
        unsigned short* tB = B0; B0 = B1; B1 = B2; B2 = tB;
    }
#undef ISSUE
#undef COMPUTE

    // Epilogue: plain bf16 stores to y_slot. C/D layout col=lane&15,
    // row=quad*4+reg (m89/m91). Pad rows skipped (never read by combine).
    #pragma unroll
    for (int i = 0; i < 4; i++) {
        #pragma unroll
        for (int r = 0; r < 4; r++) {
            int slot = m0 + wm + i * 16 + quad * 4 + r;
            if (slot >= lim) continue;
            unsigned short* yp = y_slot + (size_t)slot * HDIM + n0;
            #pragma unroll
            for (int j = 0; j < 4; j++) {
                int col = wn + j * 16 + l16;
                yp[col] = f2b(acc[i][j][r] + be[e * HDIM + n0 + col]);
            }
        }
    }
}

// ---------------------------------------------------------------------------
// K5: combine — out[t] = g0*y[s0] + g1*y[s1]. One block per token; fully
// coalesced; overwrites every out element (no out memset needed).
// ---------------------------------------------------------------------------
__global__ __launch_bounds__(256) void moe_combine(
    const unsigned short* __restrict__ y_slot,
    const int* __restrict__ tok_slot, const float* __restrict__ tok_g,
    float* __restrict__ out)
{
    int t   = blockIdx.x;
    int tid = threadIdx.x;
    int s0 = tok_slot[2 * t], s1 = tok_slot[2 * t + 1];
    float g0 = tok_g[2 * t],  g1 = tok_g[2 * t + 1];
    ushort4 a = ((const ushort4*)(y_slot + (size_t)s0 * HDIM))[tid];
    ushort4 b = ((const ushort4*)(y_slot + (size_t)s1 * HDIM))[tid];
    float4 o;
    o.x = g0 * b2f(a.x) + g1 * b2f(b.x);
    o.y = g0 * b2f(a.y) + g1 * b2f(b.y);
    o.z = g0 * b2f(a.z) + g1 * b2f(b.z);
    o.w = g0 * b2f(a.w) + g1 * b2f(b.w);
    ((float4*)(out + (size_t)t * HDIM))[tid] = o;
}

extern "C" void kernel_launch(void* const* d_in, const int* in_sizes, int n_in,
                              void* d_out, int out_size, void* d_ws, size_t ws_size,
                              hipStream_t stream) {
    const float* x  = (const float*)d_in[0];   // [B,S,D] fp32
    const float* wg = (const float*)d_in[1];   // [D,E]
    const float* we = (const float*)d_in[2];   // [E,D,H]
    const float* be = (const float*)d_in[3];   // [E,H]
    float* out = (float*)d_out;

    char* ws = (char*)d_ws;
    size_t o = 0;
    auto alloc = [&](size_t bytes) -> void* {
        void* p = ws + o;
        o = (o + bytes + 255) & ~(size_t)255;
        return p;
    };
    unsigned short* xb   = (unsigned short*)alloc((size_t)T_TOK * DDIM * 2);
    unsigned short* wtb  = (unsigned short*)alloc((size_t)NEXP * HDIM * DDIM * 2);
    unsigned short* ysl  = (unsigned short*)alloc((size_t)SLOT_CAP * HDIM * 2);
    int*   slot_token    = (int*)  alloc((size_t)SLOT_CAP * 4);
    float* slot_gate     = (float*)alloc((size_t)SLOT_CAP * 4);
    int*   counts        = (int*)  alloc(NEXP * 4);
    int*   meta          = (int*)  alloc((NEXP + 1) * 4);
    int*   tok_e         = (int*)  alloc((size_t)T_TOK * 2 * 4);
    float* tok_g         = (float*)alloc((size_t)T_TOK * 2 * 4);
    int*   tok_slot      = (int*)  alloc((size_t)T_TOK * 2 * 4);

    // 5 graph nodes total (was 9: 3 memsets + 6 kernels) — no memsets needed.
    moe_routing<<<T_TOK, 256, 0, stream>>>(x, wg, xb, tok_e, tok_g);
    moe_route_pack<<<1, 1024, 0, stream>>>(tok_e, tok_g, meta, counts,
                                           slot_token, slot_gate, tok_slot);
    moe_wtrans<<<dim3(HDIM / 64, DDIM / 64, NEXP), 256, 0, stream>>>(we, wtb);
    moe_gemm<<<dim3(HDIM / 128, SLOT_CAP / 128), 256, 0, stream>>>(
        xb, wtb, be, slot_token, meta, counts, ysl);
    moe_combine<<<T_TOK, 256, 0, stream>>>(ysl, tok_slot, tok_g, out);
}

// Round 7
// 220.152 us; speedup vs baseline: 1.3927x; 1.1407x over previous
//
#include <hip/hip_runtime.h>
#include <hip/hip_bf16.h>

// Problem constants (fixed by the reference: B=4,S=2048,D=1024,E=8,H=1024)
#define T_TOK 8192
#define DDIM  1024
#define NEXP  8
#define HDIM  1024
#define SLOT_CAP 17536   // 137 M-tiles * 128; >= 16384 + 8*127 padding worst case
#define NCBLK 32         // blocks for count/slotfill

typedef short bf16x8 __attribute__((ext_vector_type(8)));   // 8 bf16 in 4 VGPRs
typedef float f32x4  __attribute__((ext_vector_type(4)));

typedef const __attribute__((address_space(1))) unsigned int* gas_ptr;
typedef __attribute__((address_space(3))) unsigned int*       las_ptr;
#define GLD16(gp, lp) __builtin_amdgcn_global_load_lds((gas_ptr)(gp), (las_ptr)(lp), 16, 0, 0)

// fp32 -> bf16 round-to-nearest-even
static __device__ __forceinline__ unsigned short f2b(float f) {
    union { float f; unsigned int u; } v; v.f = f;
    unsigned int u = v.u;
    u += 0x7fffu + ((u >> 16) & 1u);
    return (unsigned short)(u >> 16);
}
static __device__ __forceinline__ float b2f(unsigned short h) {
    union { unsigned int u; float f; } v; v.u = ((unsigned int)h) << 16;
    return v.f;
}

// ---------------------------------------------------------------------------
// K1: routing. One block per token: fp64 logits (selection-exact vs numpy),
// softmax top-2 renormalized, 2-stage LDS reduction. Fused x -> bf16.
// (Unchanged since R3; absmax stable at 0.03125.)
// ---------------------------------------------------------------------------
__global__ __launch_bounds__(256) void moe_routing(
    const float* __restrict__ x, const float* __restrict__ wg,
    unsigned short* __restrict__ xb,
    int* __restrict__ tok_e, float* __restrict__ tok_g)
{
    __shared__ double red[256 * 9];   // [thread][expert], stride 9 (bank spread)
    __shared__ double part[64];
    __shared__ double lf[NEXP];

    int t   = blockIdx.x;
    int tid = threadIdx.x;

    float4 xv = ((const float4*)(x + (size_t)t * DDIM))[tid];
    ushort4 xs;
    xs.x = f2b(xv.x); xs.y = f2b(xv.y); xs.z = f2b(xv.z); xs.w = f2b(xv.w);
    ((ushort4*)(xb + (size_t)t * DDIM))[tid] = xs;

    double s[NEXP];
    #pragma unroll
    for (int e = 0; e < NEXP; e++) s[e] = 0.0;
    const float* wr = wg + (size_t)tid * 4 * NEXP;
    #pragma unroll
    for (int j = 0; j < 4; j++) {
        double xj = (double)((&xv.x)[j]);
        #pragma unroll
        for (int e = 0; e < NEXP; e++)
            s[e] += xj * (double)wr[j * NEXP + e];
    }
    #pragma unroll
    for (int e = 0; e < NEXP; e++) red[tid * 9 + e] = s[e];
    __syncthreads();

    if (tid < 64) {
        int e = tid >> 3, p = tid & 7;
        double acc = 0.0;
        for (int i = 0; i < 32; i++) acc += red[(i * 8 + p) * 9 + e];
        part[tid] = acc;
    }
    __syncthreads();
    if (tid < NEXP) {
        double acc = 0.0;
        #pragma unroll
        for (int p = 0; p < 8; p++) acc += part[tid * 8 + p];
        lf[tid] = acc;
    }
    __syncthreads();

    if (tid == 0) {
        double l[NEXP];
        #pragma unroll
        for (int e = 0; e < NEXP; e++) l[e] = lf[e];
        int e0 = 0;
        for (int e = 1; e < NEXP; e++) if (l[e] > l[e0]) e0 = e;
        int e1 = (e0 == 0) ? 1 : 0;
        for (int e = 0; e < NEXP; e++) if (e != e0 && l[e] > l[e1]) e1 = e;
        double g0 = 1.0 / (1.0 + exp(l[e1] - l[e0]));
        double g1 = 1.0 - g0;
        tok_e[2*t] = e0; tok_e[2*t+1] = e1;
        tok_g[2*t] = (float)g0; tok_g[2*t+1] = (float)g1;
    }
}

// ---------------------------------------------------------------------------
// K2a: per-block expert histogram -> cnt_part[b][e]. No global atomics, no
// pre-zeroed memory. (R6 lesson: the fused single-block route_pack serialized
// ~49K scattered stores on one CU; back to the R2-proven parallel structure.)
// ---------------------------------------------------------------------------
__global__ __launch_bounds__(256) void moe_count(
    const int* __restrict__ tok_e, int* __restrict__ cnt_part)
{
    __shared__ int h[NEXP];
    if (threadIdx.x < NEXP) h[threadIdx.x] = 0;
    __syncthreads();
    int t = blockIdx.x * 256 + threadIdx.x;
    atomicAdd(&h[tok_e[2*t]], 1);
    atomicAdd(&h[tok_e[2*t+1]], 1);
    __syncthreads();
    if (threadIdx.x < NEXP)
        cnt_part[blockIdx.x * NEXP + threadIdx.x] = h[threadIdx.x];
}

// K2b: reduce partials, 128-aligned prefix, init cursors. 1 block.
__global__ void moe_offsets(const int* __restrict__ cnt_part,
                            int* __restrict__ meta, int* __restrict__ counts,
                            int* __restrict__ cursor) {
    __shared__ int c_s[NEXP];
    int tid = threadIdx.x;
    if (tid < NEXP) {
        int c = 0;
        for (int b = 0; b < NCBLK; b++) c += cnt_part[b * NEXP + tid];
        counts[tid] = c; c_s[tid] = c;
    }
    __syncthreads();
    if (tid == 0) {
        int off = 0;
        for (int e = 0; e < NEXP; e++) {
            meta[e] = off;
            cursor[e] = off;
            off += (c_s[e] + 127) & ~127;
        }
        meta[NEXP] = off;
    }
}

// K2c: slot assignment. LDS-atomic local ranks + one cursor bump/expert/block
// (256 global atomics total). Also emits tok_slot for combine. Slot order
// within an expert is arbitrary — only uniqueness matters.
__global__ __launch_bounds__(256) void moe_slotfill(
    const int* __restrict__ tok_e, int* __restrict__ cursor,
    int* __restrict__ slot_token, int* __restrict__ tok_slot)
{
    __shared__ int h[NEXP];
    __shared__ int base[NEXP];
    if (threadIdx.x < NEXP) h[threadIdx.x] = 0;
    __syncthreads();
    int t = blockIdx.x * 256 + threadIdx.x;
    int e0 = tok_e[2*t],     e1 = tok_e[2*t + 1];
    int r0 = atomicAdd(&h[e0], 1);
    int r1 = atomicAdd(&h[e1], 1);
    __syncthreads();
    if (threadIdx.x < NEXP)
        base[threadIdx.x] = atomicAdd(&cursor[threadIdx.x], h[threadIdx.x]);
    __syncthreads();
    int s0 = base[e0] + r0, s1 = base[e1] + r1;
    slot_token[s0] = t;  tok_slot[2*t]     = s0;
    slot_token[s1] = t;  tok_slot[2*t + 1] = s1;
}

// K3: We [E][D][H] fp32 -> Wt [E][H][D] bf16 (transpose for GEMM B loads).
__global__ __launch_bounds__(256) void moe_wtrans(
    const float* __restrict__ we, unsigned short* __restrict__ wt)
{
    __shared__ unsigned short tile[64][65];
    int e  = blockIdx.z;
    int d0 = blockIdx.y * 64;
    int h0 = blockIdx.x * 64;
    int c  = threadIdx.x & 63;
    int r4 = threadIdx.x >> 6;
    #pragma unroll
    for (int i = 0; i < 64; i += 4)
        tile[r4 + i][c] = f2b(we[((size_t)e * DDIM + d0 + r4 + i) * HDIM + h0 + c]);
    __syncthreads();
    #pragma unroll
    for (int i = 0; i < 64; i += 4)
        wt[((size_t)e * HDIM + h0 + r4 + i) * DDIM + d0 + c] = tile[c][r4 + i];
}

// ---------------------------------------------------------------------------
// K4: grouped gather-GEMM. R6 counters: 72us, MfmaUtil 19%, Occupancy 20% —
// VGPR(136 unified) caps 3 waves/SIMD and LDS 48KB caps 3 blocks/CU; grid
// 1096/768-resident = 1.43 rounds (tail). This round targets 4 blocks/CU:
//  - launch_bounds(256,4): total regs <= 128 (frag pressure cut by loading
//    bfr[4] once and af inside the i-loop: 32 -> 20 live frag VGPRs)
//  - LDS 40KB exactly: A triple-buffered (gathered rows, far L3/HBM ->
//    distance-2), B double-buffered (2.1MB/XCD L2-resident -> distance-1)
//  - steady-state wait vmcnt(2) (A(k+1)'s 2 loads stay in flight)
// WAR safety (both depths): all GLD16s issue after the barrier, and any wave
// past barrier k has retired its iter-(k-1) ds_reads (MFMA operands consumed
// before the wave could reach the barrier).
// ---------------------------------------------------------------------------
__global__ __launch_bounds__(256, 4) void moe_gemm(
    const unsigned short* __restrict__ xb,   // [T][D] bf16
    const unsigned short* __restrict__ wt,   // [E][H][D] bf16
    const float* __restrict__ be,            // [E][H]
    const int* __restrict__ slot_token,
    const int* __restrict__ meta,
    const int* __restrict__ counts,
    unsigned short* __restrict__ y_slot)     // [SLOT_CAP][H] bf16
{
    __shared__ __align__(16) unsigned short As[3][128 * 32];   // 24 KB
    __shared__ __align__(16) unsigned short Bs[2][128 * 32];   // 16 KB

    int m0 = blockIdx.y * 128;
    if (m0 >= meta[NEXP]) return;
    int n0 = blockIdx.x * 128;

    int e = 0;
    #pragma unroll
    for (int i = 1; i < NEXP; i++) if (m0 >= meta[i]) e = i;
    int lim = meta[e] + counts[e];           // slots >= lim are padding

    int tid  = threadIdx.x;
    int lane = tid & 63, wv = tid >> 6;

    // Staging geometry: wave w owns 16-row chunks 2w,2w+1 of A and B.
    int rA = 32 * wv + (lane >> 2);
    int kc = (((lane & 3) ^ ((rA >> 1) & 3)) * 8);   // swizzled source column
    int sA0 = m0 + rA, sA1 = sA0 + 16;
    int tA0 = (sA0 < lim) ? slot_token[sA0] : 0;
    int tA1 = (sA1 < lim) ? slot_token[sA1] : 0;
    const unsigned short* gA0 = xb + (size_t)tA0 * DDIM + kc;
    const unsigned short* gA1 = xb + (size_t)tA1 * DDIM + kc;
    const unsigned short* gB0 = wt + ((size_t)e * HDIM + n0 + rA) * DDIM + kc;
    const unsigned short* gB1 = gB0 + (size_t)16 * DDIM;
    int c0 = (2 * wv) * 512;
    int c1 = c0 + 512;

    f32x4 acc[4][4];
    #pragma unroll
    for (int i = 0; i < 4; i++)
        #pragma unroll
        for (int j = 0; j < 4; j++) acc[i][j] = (f32x4){0.f, 0.f, 0.f, 0.f};

    int wm = (wv >> 1) * 64, wn = (wv & 1) * 64;
    int l16 = lane & 15, quad = lane >> 4;
    int f = (l16 >> 1) & 3;
    int rdA[4], rdB[4];
    #pragma unroll
    for (int i = 0; i < 4; i++) {
        rdA[i] = (wm + i * 16 + l16) * 32 + ((quad ^ f) * 8);
        rdB[i] = (wn + i * 16 + l16) * 32 + ((quad ^ f) * 8);
    }

#define ISSUE_A(kkv, Ab)                                                      \
    {                                                                         \
        int ko = (kkv) * 32;                                                  \
        GLD16(gA0 + ko, (Ab) + c0);                                           \
        GLD16(gA1 + ko, (Ab) + c1);                                           \
    }
#define ISSUE_B(kkv, Bb)                                                      \
    {                                                                         \
        int ko = (kkv) * 32;                                                  \
        GLD16(gB0 + ko, (Bb) + c0);                                           \
        GLD16(gB1 + ko, (Bb) + c1);                                           \
    }
#define COMPUTE(Ab, Bb)                                                       \
    {                                                                         \
        bf16x8 bfr[4];                                                        \
        _Pragma("unroll")                                                     \
        for (int j = 0; j < 4; j++)                                           \
            bfr[j] = *(const bf16x8*)((Bb) + rdB[j]);                         \
        _Pragma("unroll")                                                     \
        for (int i = 0; i < 4; i++) {                                         \
            bf16x8 af = *(const bf16x8*)((Ab) + rdA[i]);                      \
            _Pragma("unroll")                                                 \
            for (int j = 0; j < 4; j++)                                       \
                acc[i][j] = __builtin_amdgcn_mfma_f32_16x16x32_bf16(          \
                    af, bfr[j], acc[i][j], 0, 0, 0);                          \
        }                                                                     \
    }

    unsigned short *A0 = As[0], *A1 = As[1], *A2 = As[2];
    unsigned short *B0 = Bs[0], *B1 = Bs[1];

    // FIFO: A(0), B(0), A(1)  -> first wait vmcnt(2) covers A0,B0.
    ISSUE_A(0, A0)
    ISSUE_B(0, B0)
    ISSUE_A(1, A1)

    #pragma unroll 1
    for (int kk = 0; kk < 32; ++kk) {
        asm volatile("" ::: "memory");
        if (kk == 31) __builtin_amdgcn_s_waitcnt(0x0F70);  // vmcnt(0) tail
        else          __builtin_amdgcn_s_waitcnt(0x0F72);  // vmcnt(2)
        __builtin_amdgcn_s_barrier();
        asm volatile("" ::: "memory");
        COMPUTE(A0, B0)
        if (kk < 31) ISSUE_B(kk + 1, B1)      // B: distance-1 (L2-resident)
        if (kk < 30) ISSUE_A(kk + 2, A2)      // A: distance-2 (far gather)
        unsigned short* tA = A0; A0 = A1; A1 = A2; A2 = tA;
        unsigned short* tB = B0; B0 = B1; B1 = tB;
    }
#undef ISSUE_A
#undef ISSUE_B
#undef COMPUTE

    // Epilogue: plain bf16 stores to y_slot. C/D layout col=lane&15,
    // row=quad*4+reg (m89/m91). Pad rows skipped (never read by combine).
    #pragma unroll
    for (int i = 0; i < 4; i++) {
        #pragma unroll
        for (int r = 0; r < 4; r++) {
            int slot = m0 + wm + i * 16 + quad * 4 + r;
            if (slot >= lim) continue;
            unsigned short* yp = y_slot + (size_t)slot * HDIM + n0;
            #pragma unroll
            for (int j = 0; j < 4; j++) {
                int col = wn + j * 16 + l16;
                yp[col] = f2b(acc[i][j][r] + be[e * HDIM + n0 + col]);
            }
        }
    }
}

// ---------------------------------------------------------------------------
// K5: combine — out[t] = g0*y[s0] + g1*y[s1]. One block per token; fully
// coalesced; overwrites every out element (no out memset needed).
// ---------------------------------------------------------------------------
__global__ __launch_bounds__(256) void moe_combine(
    const unsigned short* __restrict__ y_slot,
    const int* __restrict__ tok_slot, const float* __restrict__ tok_g,
    float* __restrict__ out)
{
    int t   = blockIdx.x;
    int tid = threadIdx.x;
    int s0 = tok_slot[2 * t], s1 = tok_slot[2 * t + 1];
    float g0 = tok_g[2 * t],  g1 = tok_g[2 * t + 1];
    ushort4 a = ((const ushort4*)(y_slot + (size_t)s0 * HDIM))[tid];
    ushort4 b = ((const ushort4*)(y_slot + (size_t)s1 * HDIM))[tid];
    float4 o;
    o.x = g0 * b2f(a.x) + g1 * b2f(b.x);
    o.y = g0 * b2f(a.y) + g1 * b2f(b.y);
    o.z = g0 * b2f(a.z) + g1 * b2f(b.z);
    o.w = g0 * b2f(a.w) + g1 * b2f(b.w);
    ((float4*)(out + (size_t)t * HDIM))[tid] = o;
}

extern "C" void kernel_launch(void* const* d_in, const int* in_sizes, int n_in,
                              void* d_out, int out_size, void* d_ws, size_t ws_size,
                              hipStream_t stream) {
    const float* x  = (const float*)d_in[0];   // [B,S,D] fp32
    const float* wg = (const float*)d_in[1];   // [D,E]
    const float* we = (const float*)d_in[2];   // [E,D,H]
    const float* be = (const float*)d_in[3];   // [E,H]
    float* out = (float*)d_out;

    char* ws = (char*)d_ws;
    size_t o = 0;
    auto alloc = [&](size_t bytes) -> void* {
        void* p = ws + o;
        o = (o + bytes + 255) & ~(size_t)255;
        return p;
    };
    unsigned short* xb   = (unsigned short*)alloc((size_t)T_TOK * DDIM * 2);
    unsigned short* wtb  = (unsigned short*)alloc((size_t)NEXP * HDIM * DDIM * 2);
    unsigned short* ysl  = (unsigned short*)alloc((size_t)SLOT_CAP * HDIM * 2);
    int*   slot_token    = (int*)  alloc((size_t)SLOT_CAP * 4);
    int*   cnt_part      = (int*)  alloc((size_t)NCBLK * NEXP * 4);
    int*   counts        = (int*)  alloc(NEXP * 4);
    int*   meta          = (int*)  alloc((NEXP + 1) * 4);
    int*   cursor        = (int*)  alloc(NEXP * 4);
    int*   tok_e         = (int*)  alloc((size_t)T_TOK * 2 * 4);
    float* tok_g         = (float*)alloc((size_t)T_TOK * 2 * 4);
    int*   tok_slot      = (int*)  alloc((size_t)T_TOK * 2 * 4);

    // 7 graph nodes, no memsets.
    moe_routing<<<T_TOK, 256, 0, stream>>>(x, wg, xb, tok_e, tok_g);
    moe_count<<<NCBLK, 256, 0, stream>>>(tok_e, cnt_part);
    moe_offsets<<<1, 64, 0, stream>>>(cnt_part, meta, counts, cursor);
    moe_slotfill<<<NCBLK, 256, 0, stream>>>(tok_e, cursor, slot_token, tok_slot);
    moe_wtrans<<<dim3(HDIM / 64, DDIM / 64, NEXP), 256, 0, stream>>>(we, wtb);
    moe_gemm<<<dim3(HDIM / 128, SLOT_CAP / 128), 256, 0, stream>>>(
        xb, wtb, be, slot_token, meta, counts, ysl);
    moe_combine<<<T_TOK, 256, 0, stream>>>(ysl, tok_slot, tok_g, out);
}